// Round 3
// baseline (297.868 us; speedup 1.0000x reference)
//
#include <hip/hip_runtime.h>

#define N_NODES 50000
#define N_EDGES 800000
#define IN_DIM 128
#define OUT_DIM 64
#define ROWS 64   // rows per block in gemm

// ---------------------------------------------------------------------------
// Kernel 1: h = x @ w   (x: [N,128] f32, w: [128,64] f32, h: [N,64] f32)
// 256 threads = 16 dim-groups x 16 row-groups; each thread 4 rows x 4 dims.
// ---------------------------------------------------------------------------
__global__ __launch_bounds__(256, 2) void gc_gemm(const float* __restrict__ x,
                                                  const float* __restrict__ w,
                                                  float* __restrict__ h) {
    __shared__ float w_lds[IN_DIM * OUT_DIM];   // 32 KB
    __shared__ float x_lds[ROWS * IN_DIM];      // 32 KB (swizzled)

    const int tid = threadIdx.x;
    const int row0 = blockIdx.x * ROWS;

    const float4* w4 = reinterpret_cast<const float4*>(w);
    float4* wl4 = reinterpret_cast<float4*>(w_lds);
#pragma unroll
    for (int i = 0; i < 8; ++i) wl4[tid + i * 256] = w4[tid + i * 256];

    const float4* x4 = reinterpret_cast<const float4*>(x);
    float4* xl4 = reinterpret_cast<float4*>(x_lds);
#pragma unroll
    for (int i = 0; i < 8; ++i) {
        const int idx = tid + i * 256;
        const int r = idx >> 5;          // 32 float4 per row
        const int kc = idx & 31;
        const int g = row0 + r;
        float4 v = make_float4(0.f, 0.f, 0.f, 0.f);
        if (g < N_NODES) v = x4[(size_t)g * 32 + kc];
        xl4[r * 32 + (kc ^ (r & 3))] = v;
    }
    __syncthreads();

    const int tx = tid & 15;
    const int ty = tid >> 4;
    const int sw = ty & 3;

    float4 acc[4];
#pragma unroll
    for (int i = 0; i < 4; ++i) acc[i] = make_float4(0.f, 0.f, 0.f, 0.f);

    for (int kc = 0; kc < 32; ++kc) {
        float4 xv[4], wv[4];
#pragma unroll
        for (int i = 0; i < 4; ++i)
            xv[i] = xl4[(ty + 16 * i) * 32 + (kc ^ sw)];
#pragma unroll
        for (int j = 0; j < 4; ++j)
            wv[j] = wl4[(kc * 4 + j) * 16 + tx];
#pragma unroll
        for (int i = 0; i < 4; ++i) {
            acc[i].x = fmaf(xv[i].x, wv[0].x, acc[i].x);
            acc[i].y = fmaf(xv[i].x, wv[0].y, acc[i].y);
            acc[i].z = fmaf(xv[i].x, wv[0].z, acc[i].z);
            acc[i].w = fmaf(xv[i].x, wv[0].w, acc[i].w);
            acc[i].x = fmaf(xv[i].y, wv[1].x, acc[i].x);
            acc[i].y = fmaf(xv[i].y, wv[1].y, acc[i].y);
            acc[i].z = fmaf(xv[i].y, wv[1].z, acc[i].z);
            acc[i].w = fmaf(xv[i].y, wv[1].w, acc[i].w);
            acc[i].x = fmaf(xv[i].z, wv[2].x, acc[i].x);
            acc[i].y = fmaf(xv[i].z, wv[2].y, acc[i].y);
            acc[i].z = fmaf(xv[i].z, wv[2].z, acc[i].z);
            acc[i].w = fmaf(xv[i].z, wv[2].w, acc[i].w);
            acc[i].x = fmaf(xv[i].w, wv[3].x, acc[i].x);
            acc[i].y = fmaf(xv[i].w, wv[3].y, acc[i].y);
            acc[i].z = fmaf(xv[i].w, wv[3].z, acc[i].z);
            acc[i].w = fmaf(xv[i].w, wv[3].w, acc[i].w);
        }
    }

    float4* h4 = reinterpret_cast<float4*>(h);
#pragma unroll
    for (int i = 0; i < 4; ++i) {
        const int r = row0 + ty + 16 * i;
        if (r < N_NODES) h4[(size_t)r * 16 + tx] = acc[i];
    }
}

// ---------------------------------------------------------------------------
// CSR build, step 1: histogram of destinations. offs[] pre-zeroed.
// ---------------------------------------------------------------------------
__global__ __launch_bounds__(256) void gc_hist(const int* __restrict__ edst,
                                               int* __restrict__ offs) {
    const int e = blockIdx.x * 256 + threadIdx.x;   // grid exact: 3125*256
    atomicAdd(&offs[edst[e]], 1);
}

// ---------------------------------------------------------------------------
// CSR build, step 2: in-place exclusive prefix sum over offs[50000].
// Single block, 256 threads x 196 elements each (255*196+20 = 50000).
// ---------------------------------------------------------------------------
#define SCAN_CHUNK 196
__global__ __launch_bounds__(256) void gc_scan(int* __restrict__ offs) {
    __shared__ int part[256];
    const int t = threadIdx.x;
    const int base = t * SCAN_CHUNK;
    const int n = (base < N_NODES) ? min(SCAN_CHUNK, N_NODES - base) : 0;

    int sum = 0;
    for (int i = 0; i < n; ++i) sum += offs[base + i];
    part[t] = sum;
    __syncthreads();

    // Hillis-Steele inclusive scan of the 256 partials.
    for (int off = 1; off < 256; off <<= 1) {
        int v = (t >= off) ? part[t - off] : 0;
        __syncthreads();
        part[t] += v;
        __syncthreads();
    }

    int run = part[t] - sum;   // exclusive prefix for this chunk
    for (int i = 0; i < n; ++i) {
        int c = offs[base + i];
        offs[base + i] = run;
        run += c;
    }
}

// ---------------------------------------------------------------------------
// CSR build, step 3: reorder edges by destination.
// Uses offs[] as cursors; afterwards offs[i] == end of row i == start of i+1.
// ---------------------------------------------------------------------------
__global__ __launch_bounds__(256) void gc_reorder(const int* __restrict__ esrc,
                                                  const int* __restrict__ edst,
                                                  const float* __restrict__ ew,
                                                  int* __restrict__ offs,
                                                  int* __restrict__ csr_src,
                                                  float* __restrict__ csr_w) {
    const int e = blockIdx.x * 256 + threadIdx.x;   // grid exact
    const int d = edst[e];
    const int pos = atomicAdd(&offs[d], 1);
    csr_src[pos] = esrc[e];
    csr_w[pos] = ew[e];
}

// ---------------------------------------------------------------------------
// Kernel 4: wave-per-node gather-accumulate + fused ReLU.
// After reorder: row i spans [i ? offs[i-1] : 0, offs[i]).
// lane d accumulates sum_j csr_w[j] * h[csr_src[j]][d] in a register.
// ---------------------------------------------------------------------------
__global__ __launch_bounds__(256) void gc_aggregate(const float* __restrict__ h,
                                                    const int* __restrict__ offs,
                                                    const int* __restrict__ csr_src,
                                                    const float* __restrict__ csr_w,
                                                    float* __restrict__ out) {
    const int node = __builtin_amdgcn_readfirstlane(blockIdx.x * 4 + (threadIdx.x >> 6));
    const int lane = threadIdx.x & 63;

    const int beg = __builtin_amdgcn_readfirstlane(node ? offs[node - 1] : 0);
    const int end = __builtin_amdgcn_readfirstlane(offs[node]);

    float acc = 0.0f;
    int j = beg;
    for (; j + 4 <= end; j += 4) {
        const int s0 = __builtin_amdgcn_readfirstlane(csr_src[j + 0]);
        const int s1 = __builtin_amdgcn_readfirstlane(csr_src[j + 1]);
        const int s2 = __builtin_amdgcn_readfirstlane(csr_src[j + 2]);
        const int s3 = __builtin_amdgcn_readfirstlane(csr_src[j + 3]);
        const float w0 = csr_w[j + 0];
        const float w1 = csr_w[j + 1];
        const float w2 = csr_w[j + 2];
        const float w3 = csr_w[j + 3];
        const float v0 = h[(size_t)s0 * OUT_DIM + lane];
        const float v1 = h[(size_t)s1 * OUT_DIM + lane];
        const float v2 = h[(size_t)s2 * OUT_DIM + lane];
        const float v3 = h[(size_t)s3 * OUT_DIM + lane];
        acc = fmaf(w0, v0, acc);
        acc = fmaf(w1, v1, acc);
        acc = fmaf(w2, v2, acc);
        acc = fmaf(w3, v3, acc);
    }
    for (; j < end; ++j) {
        const int s = __builtin_amdgcn_readfirstlane(csr_src[j]);
        acc = fmaf(csr_w[j], h[(size_t)s * OUT_DIM + lane], acc);
    }

    out[(size_t)node * OUT_DIM + lane] = fmaxf(acc, 0.0f);
}

extern "C" void kernel_launch(void* const* d_in, const int* in_sizes, int n_in,
                              void* d_out, int out_size, void* d_ws, size_t ws_size,
                              hipStream_t stream) {
    const float* x    = (const float*)d_in[0];
    const int*   esrc = (const int*)d_in[1];
    const int*   edst = (const int*)d_in[2];
    const float* ew   = (const float*)d_in[3];
    const float* w    = (const float*)d_in[4];
    float* out = (float*)d_out;

    // Workspace layout (~19.5 MB):
    float* h       = (float*)d_ws;                         // 3,200,000 f32
    int*   offs    = (int*)(h + (size_t)N_NODES * OUT_DIM);// 50,000 int
    int*   csr_src = offs + 50048;                         // 800,000 int (aligned)
    float* csr_w   = (float*)(csr_src + N_EDGES);          // 800,000 f32

    // h = x @ w
    gc_gemm<<<(N_NODES + ROWS - 1) / ROWS, 256, 0, stream>>>(x, w, h);

    // CSR build (runs every call; d_ws is re-poisoned by the harness).
    hipMemsetAsync(offs, 0, (size_t)N_NODES * sizeof(int), stream);
    gc_hist<<<N_EDGES / 256, 256, 0, stream>>>(edst, offs);
    gc_scan<<<1, 256, 0, stream>>>(offs);
    gc_reorder<<<N_EDGES / 256, 256, 0, stream>>>(esrc, edst, ew, offs, csr_src, csr_w);

    // out[i] = relu( sum_{e: dst=i} w_e * h[src_e] )
    gc_aggregate<<<N_NODES / 4, 256, 0, stream>>>(h, offs, csr_src, csr_w, out);
}

// Round 4
// 219.303 us; speedup vs baseline: 1.3582x; 1.3582x over previous
//
#include <hip/hip_runtime.h>

#define N_NODES 50000
#define N_EDGES 800000
#define IN_DIM 128
#define OUT_DIM 64
#define ROWS 64          // rows per block in gemm
#define SCAN_BLK 512     // elements per scan block
#define NB_SCAN ((N_NODES + SCAN_BLK - 1) / SCAN_BLK)   // 98

// ---------------------------------------------------------------------------
// Kernel 1: h = x @ w   (x: [N,128] f32, w: [128,64] f32, h: [N,64] f32)
// 256 threads = 16 dim-groups x 16 row-groups; each thread 4 rows x 4 dims.
// ---------------------------------------------------------------------------
__global__ __launch_bounds__(256, 2) void gc_gemm(const float* __restrict__ x,
                                                  const float* __restrict__ w,
                                                  float* __restrict__ h) {
    __shared__ float w_lds[IN_DIM * OUT_DIM];   // 32 KB
    __shared__ float x_lds[ROWS * IN_DIM];      // 32 KB (swizzled)

    const int tid = threadIdx.x;
    const int row0 = blockIdx.x * ROWS;

    const float4* w4 = reinterpret_cast<const float4*>(w);
    float4* wl4 = reinterpret_cast<float4*>(w_lds);
#pragma unroll
    for (int i = 0; i < 8; ++i) wl4[tid + i * 256] = w4[tid + i * 256];

    const float4* x4 = reinterpret_cast<const float4*>(x);
    float4* xl4 = reinterpret_cast<float4*>(x_lds);
#pragma unroll
    for (int i = 0; i < 8; ++i) {
        const int idx = tid + i * 256;
        const int r = idx >> 5;          // 32 float4 per row
        const int kc = idx & 31;
        const int g = row0 + r;
        float4 v = make_float4(0.f, 0.f, 0.f, 0.f);
        if (g < N_NODES) v = x4[(size_t)g * 32 + kc];
        xl4[r * 32 + (kc ^ (r & 3))] = v;
    }
    __syncthreads();

    const int tx = tid & 15;
    const int ty = tid >> 4;
    const int sw = ty & 3;

    float4 acc[4];
#pragma unroll
    for (int i = 0; i < 4; ++i) acc[i] = make_float4(0.f, 0.f, 0.f, 0.f);

    for (int kc = 0; kc < 32; ++kc) {
        float4 xv[4], wv[4];
#pragma unroll
        for (int i = 0; i < 4; ++i)
            xv[i] = xl4[(ty + 16 * i) * 32 + (kc ^ sw)];
#pragma unroll
        for (int j = 0; j < 4; ++j)
            wv[j] = wl4[(kc * 4 + j) * 16 + tx];
#pragma unroll
        for (int i = 0; i < 4; ++i) {
            acc[i].x = fmaf(xv[i].x, wv[0].x, acc[i].x);
            acc[i].y = fmaf(xv[i].x, wv[0].y, acc[i].y);
            acc[i].z = fmaf(xv[i].x, wv[0].z, acc[i].z);
            acc[i].w = fmaf(xv[i].x, wv[0].w, acc[i].w);
            acc[i].x = fmaf(xv[i].y, wv[1].x, acc[i].x);
            acc[i].y = fmaf(xv[i].y, wv[1].y, acc[i].y);
            acc[i].z = fmaf(xv[i].y, wv[1].z, acc[i].z);
            acc[i].w = fmaf(xv[i].y, wv[1].w, acc[i].w);
            acc[i].x = fmaf(xv[i].z, wv[2].x, acc[i].x);
            acc[i].y = fmaf(xv[i].z, wv[2].y, acc[i].y);
            acc[i].z = fmaf(xv[i].z, wv[2].z, acc[i].z);
            acc[i].w = fmaf(xv[i].z, wv[2].w, acc[i].w);
            acc[i].x = fmaf(xv[i].w, wv[3].x, acc[i].x);
            acc[i].y = fmaf(xv[i].w, wv[3].y, acc[i].y);
            acc[i].z = fmaf(xv[i].w, wv[3].z, acc[i].z);
            acc[i].w = fmaf(xv[i].w, wv[3].w, acc[i].w);
        }
    }

    float4* h4 = reinterpret_cast<float4*>(h);
#pragma unroll
    for (int i = 0; i < 4; ++i) {
        const int r = row0 + ty + 16 * i;
        if (r < N_NODES) h4[(size_t)r * 16 + tx] = acc[i];
    }
}

// ---------------------------------------------------------------------------
// CSR build, step 1: histogram of destinations. offs[] pre-zeroed.
// ---------------------------------------------------------------------------
__global__ __launch_bounds__(256) void gc_hist(const int* __restrict__ edst,
                                               int* __restrict__ offs) {
    const int e = blockIdx.x * 256 + threadIdx.x;   // grid exact: 3125*256
    atomicAdd(&offs[edst[e]], 1);
}

// ---------------------------------------------------------------------------
// Parallel exclusive scan of offs[50000], 3 passes.
// Pass A: per-block (512-elem chunk) sums -> bsum[98].
// ---------------------------------------------------------------------------
__global__ __launch_bounds__(256) void gc_scan1(const int* __restrict__ offs,
                                                int* __restrict__ bsum) {
    __shared__ int red[256];
    const int t = threadIdx.x;
    const int i0 = blockIdx.x * SCAN_BLK + t * 2;
    int v = 0;
    if (i0 < N_NODES) v += offs[i0];
    if (i0 + 1 < N_NODES) v += offs[i0 + 1];
    red[t] = v;
    __syncthreads();
#pragma unroll
    for (int s = 128; s > 0; s >>= 1) {
        if (t < s) red[t] += red[t + s];
        __syncthreads();
    }
    if (t == 0) bsum[blockIdx.x] = red[0];
}

// Pass B: single small block scans the 98 partials in-place (-> exclusive).
__global__ __launch_bounds__(128) void gc_scan2(int* __restrict__ bsum) {
    __shared__ int part[128];
    const int t = threadIdx.x;
    const int v = (t < NB_SCAN) ? bsum[t] : 0;
    part[t] = v;
    __syncthreads();
#pragma unroll
    for (int off = 1; off < 128; off <<= 1) {
        const int u = (t >= off) ? part[t - off] : 0;
        __syncthreads();
        part[t] += u;
        __syncthreads();
    }
    if (t < NB_SCAN) bsum[t] = part[t] - v;   // exclusive prefix of block sums
}

// Pass C: per-block local exclusive scan + block offset, in-place on offs.
__global__ __launch_bounds__(256) void gc_scan3(int* __restrict__ offs,
                                                const int* __restrict__ bsum) {
    __shared__ int part[256];
    const int t = threadIdx.x;
    const int i0 = blockIdx.x * SCAN_BLK + t * 2;
    const int v0 = (i0 < N_NODES) ? offs[i0] : 0;
    const int v1 = (i0 + 1 < N_NODES) ? offs[i0 + 1] : 0;
    const int s = v0 + v1;
    part[t] = s;
    __syncthreads();
#pragma unroll
    for (int off = 1; off < 256; off <<= 1) {
        const int u = (t >= off) ? part[t - off] : 0;
        __syncthreads();
        part[t] += u;
        __syncthreads();
    }
    const int pre = bsum[blockIdx.x] + part[t] - s;   // exclusive for elem i0
    if (i0 < N_NODES) offs[i0] = pre;
    if (i0 + 1 < N_NODES) offs[i0 + 1] = pre + v0;
}

// ---------------------------------------------------------------------------
// CSR build, step 3: reorder edges by destination into packed (src, w) pairs.
// Uses offs[] as cursors; afterwards offs[i] == end of row i.
// ---------------------------------------------------------------------------
__global__ __launch_bounds__(256) void gc_reorder(const int* __restrict__ esrc,
                                                  const int* __restrict__ edst,
                                                  const float* __restrict__ ew,
                                                  int* __restrict__ offs,
                                                  int2* __restrict__ csr) {
    const int e = blockIdx.x * 256 + threadIdx.x;   // grid exact
    const int d = edst[e];
    const int pos = atomicAdd(&offs[d], 1);
    csr[pos] = make_int2(esrc[e], __float_as_int(ew[e]));
}

// ---------------------------------------------------------------------------
// Kernel 4: wave-per-node gather-accumulate + fused ReLU.
// Row i spans [i ? offs[i-1] : 0, offs[i]).
// ---------------------------------------------------------------------------
__global__ __launch_bounds__(256) void gc_aggregate(const float* __restrict__ h,
                                                    const int* __restrict__ offs,
                                                    const int2* __restrict__ csr,
                                                    float* __restrict__ out) {
    const int node = __builtin_amdgcn_readfirstlane(blockIdx.x * 4 + (threadIdx.x >> 6));
    const int lane = threadIdx.x & 63;

    const int beg = __builtin_amdgcn_readfirstlane(node ? offs[node - 1] : 0);
    const int end = __builtin_amdgcn_readfirstlane(offs[node]);

    float acc = 0.0f;
    int j = beg;
    for (; j + 4 <= end; j += 4) {
        const int2 e0 = csr[j + 0];
        const int2 e1 = csr[j + 1];
        const int2 e2 = csr[j + 2];
        const int2 e3 = csr[j + 3];
        const int s0 = __builtin_amdgcn_readfirstlane(e0.x);
        const int s1 = __builtin_amdgcn_readfirstlane(e1.x);
        const int s2 = __builtin_amdgcn_readfirstlane(e2.x);
        const int s3 = __builtin_amdgcn_readfirstlane(e3.x);
        const float v0 = h[(size_t)s0 * OUT_DIM + lane];
        const float v1 = h[(size_t)s1 * OUT_DIM + lane];
        const float v2 = h[(size_t)s2 * OUT_DIM + lane];
        const float v3 = h[(size_t)s3 * OUT_DIM + lane];
        acc = fmaf(__int_as_float(e0.y), v0, acc);
        acc = fmaf(__int_as_float(e1.y), v1, acc);
        acc = fmaf(__int_as_float(e2.y), v2, acc);
        acc = fmaf(__int_as_float(e3.y), v3, acc);
    }
    for (; j < end; ++j) {
        const int2 e = csr[j];
        const int s = __builtin_amdgcn_readfirstlane(e.x);
        acc = fmaf(__int_as_float(e.y), h[(size_t)s * OUT_DIM + lane], acc);
    }

    out[(size_t)node * OUT_DIM + lane] = fmaxf(acc, 0.0f);
}

extern "C" void kernel_launch(void* const* d_in, const int* in_sizes, int n_in,
                              void* d_out, int out_size, void* d_ws, size_t ws_size,
                              hipStream_t stream) {
    const float* x    = (const float*)d_in[0];
    const int*   esrc = (const int*)d_in[1];
    const int*   edst = (const int*)d_in[2];
    const float* ew   = (const float*)d_in[3];
    const float* w    = (const float*)d_in[4];
    float* out = (float*)d_out;

    // Workspace layout (~19.6 MB):
    float* h    = (float*)d_ws;                               // 3,200,000 f32
    int*   offs = (int*)(h + (size_t)N_NODES * OUT_DIM);      // 50,000 int
    int*   bsum = offs + 50048;                               // 128 int
    int2*  csr  = (int2*)(bsum + 128);                        // 800,000 int2

    // h = x @ w
    gc_gemm<<<(N_NODES + ROWS - 1) / ROWS, 256, 0, stream>>>(x, w, h);

    // CSR build (runs fresh every call).
    hipMemsetAsync(offs, 0, (size_t)N_NODES * sizeof(int), stream);
    gc_hist<<<N_EDGES / 256, 256, 0, stream>>>(edst, offs);
    gc_scan1<<<NB_SCAN, 256, 0, stream>>>(offs, bsum);
    gc_scan2<<<1, 128, 0, stream>>>(bsum);
    gc_scan3<<<NB_SCAN, 256, 0, stream>>>(offs, bsum);
    gc_reorder<<<N_EDGES / 256, 256, 0, stream>>>(esrc, edst, ew, offs, csr);

    // out[i] = relu( sum_{e: dst=i} w_e * h[src_e] )
    gc_aggregate<<<N_NODES / 4, 256, 0, stream>>>(h, offs, csr, out);
}